// Round 13
// baseline (303.624 us; speedup 1.0000x reference)
//
#include <hip/hip_runtime.h>

// ---------------------------------------------------------------------------
// AttentionMultiHead: x[8,1024,1024] f32, per-head Wq/Wk/Wv[16,1024,64]+bias,
// Wo[1024,64]+bo. Outputs: z_out[8,1024,64] f32, att[8,16,1024,1024] f32 (raw).
//
// Ledger after R12 (229.1us): attn ~120 (floor ~93), gemm_qkv ~55, packs ~25,
// out ~8. Confirmed mechanisms: VMEM request-rate (R11 load-coalesce -70us;
// R12 128B-full-line store flush -49us). R13: kill the per-group barrier
// stalls in attn: (a) 64-kv double-buffered K/V staging, stage(g+1) issued
// BEFORE compute(g) so the end-of-group __syncthreads vmcnt drain finds it
// already complete (LDS 47KB keeps 3 blocks/CU - avoids R5's occupancy trap);
// (b) att flush stores nt->cached: lines are now fully covered 128B so no
// write-allocate RMW, and cached stores ack from L2 at barriers instead of
// HBM-side nt ack (the per-group drain cost).
// ---------------------------------------------------------------------------

typedef __bf16 bf16x8 __attribute__((ext_vector_type(8)));
typedef float f32x4 __attribute__((ext_vector_type(4)));
typedef unsigned short u16x8 __attribute__((ext_vector_type(8)));
typedef unsigned short u16x4 __attribute__((ext_vector_type(4)));

typedef __attribute__((address_space(1))) unsigned int as1_u32;
typedef __attribute__((address_space(3))) unsigned int as3_u32;

#define MFMA16(a, b, c) __builtin_amdgcn_mfma_f32_16x16x32_bf16(a, b, c, 0, 0, 0)

__device__ __forceinline__ void gload_lds16(const void* g, void* l) {
  __builtin_amdgcn_global_load_lds((const as1_u32*)g, (as3_u32*)l, 16, 0, 0);
}

__device__ __forceinline__ unsigned short f2bf(float f) {
  union { float f; unsigned u; } a; a.f = f;
  unsigned r = a.u + 0x7FFFu + ((a.u >> 16) & 1u);  // RNE
  return (unsigned short)(r >> 16);
}

// ---------------- fused pack kernel ----------------
__global__ __launch_bounds__(256) void pack_all(const float* __restrict__ x, const float* __restrict__ Wq,
                                                const float* __restrict__ Wk, const float* __restrict__ Wv,
                                                const float* __restrict__ Wo, const float* __restrict__ bq,
                                                const float* __restrict__ bk, const float* __restrict__ bv,
                                                ushort* __restrict__ xb, ushort* __restrict__ Wp,
                                                ushort* __restrict__ Wop, float* __restrict__ bqkv) {
  const int bid = blockIdx.x;
  if (bid < 8192) {
    const size_t i = ((size_t)bid * 256 + threadIdx.x) * 4;
    const float4 v = *(const float4*)(x + i);
    u16x4 o; o[0] = f2bf(v.x); o[1] = f2bf(v.y); o[2] = f2bf(v.z); o[3] = f2bf(v.w);
    *(u16x4*)(xb + i) = o;
  } else if (bid < 20480) {
    const int b2 = bid - 8192;
    const int swz = (b2 & 7) * 1536 + (b2 >> 3);
    const int o = swz * 256 + threadIdx.x;  // 0 .. 3072*1024
    const int n = o >> 10, d = o & 1023;
    const int proj = n >> 10, hk = n & 1023;
    const float* W = proj == 0 ? Wq : (proj == 1 ? Wk : Wv);
    const int h = hk >> 6, kk = hk & 63;
    Wp[o] = f2bf(W[((size_t)h * 1024 + d) * 64 + kk]);
  } else {
    const int idx = (bid - 20480) * 256 + threadIdx.x;
    if (idx < 65536) {
      const int n = idx >> 10, c = idx & 1023;   // Wop[n][c] = Wo[c][n]
      Wop[idx] = f2bf(Wo[c * 64 + n]);
    } else if (idx < 65536 + 3072) {
      const int n = idx - 65536;
      const int proj = n >> 10;
      const float* bb = proj == 0 ? bq : (proj == 1 ? bk : bv);
      bqkv[n] = bb[n & 1023];
    }
  }
}

// ---------------- QKV projection GEMM (R3 structure) ----------------
__global__ __launch_bounds__(256) void gemm_qkv(const ushort* __restrict__ xb, const ushort* __restrict__ Wp,
                                                const float* __restrict__ bqkv, ushort* __restrict__ qo,
                                                ushort* __restrict__ ko, ushort* __restrict__ vTo) {
  __shared__ ushort As[128 * 32], Bs[128 * 32];
  const int bid = blockIdx.x;                 // 1536 blocks
  const int swz = (bid & 7) * 192 + (bid >> 3);
  const int by = swz / 24, bx = swz - by * 24;
  const int t = threadIdx.x, w = t >> 6, l = t & 63, lg = l >> 4, lr = l & 15;
  const int m0 = by * 128, n0 = bx * 128;
  const int wm = w >> 1, wn = w & 1;
  const int srow = l >> 2, sslot = l & 3;
  f32x4 acc[4][4] = {};
  for (int kt = 0; kt < 32; ++kt) {
    __syncthreads();
#pragma unroll
    for (int c = 0; c < 2; ++c) {
      const int cc = w * 2 + c;              // 0..7, 1KB chunk per wave-call
      const int row = cc * 16 + srow;        // LDS linear == row*64B + slot*16B
      gload_lds16(xb + (size_t)(m0 + row) * 1024 + kt * 32 + sslot * 8, &As[cc * 512]);
      gload_lds16(Wp + (size_t)(n0 + row) * 1024 + kt * 32 + sslot * 8, &Bs[cc * 512]);
    }
    __syncthreads();
    bf16x8 af[4], bfr[4];
#pragma unroll
    for (int mt = 0; mt < 4; ++mt)
      af[mt] = *(const bf16x8*)(&As[(wm * 64 + mt * 16 + lr) * 32 + lg * 8]);
#pragma unroll
    for (int nt = 0; nt < 4; ++nt)
      bfr[nt] = *(const bf16x8*)(&Bs[(wn * 64 + nt * 16 + lr) * 32 + lg * 8]);
#pragma unroll
    for (int mt = 0; mt < 4; ++mt)
#pragma unroll
      for (int nt = 0; nt < 4; ++nt)
        acc[mt][nt] = MFMA16(af[mt], bfr[nt], acc[mt][nt]);
  }
  // epilogue: bias + relu -> bf16. proj uniform across the wave (16-aligned n-chunks).
#pragma unroll
  for (int nt = 0; nt < 4; ++nt) {
    const int n = n0 + wn * 64 + nt * 16 + lr;
    const float bias = bqkv[n];
    const int proj = n >> 10, h = (n >> 6) & 15, dk = n & 63;
#pragma unroll
    for (int mt = 0; mt < 4; ++mt) {
      const int mb = m0 + wm * 64 + mt * 16 + lg * 4;  // j-quad base, same b & 4-aligned s
      const int b = mb >> 10, s = mb & 1023;
      float vv[4];
#pragma unroll
      for (int j = 0; j < 4; ++j) {
        float a = acc[mt][nt][j] + bias;
        vv[j] = a > 0.f ? a : 0.f;
      }
      if (proj == 2) {
        u16x4 o; o[0] = f2bf(vv[0]); o[1] = f2bf(vv[1]); o[2] = f2bf(vv[2]); o[3] = f2bf(vv[3]);
        *(u16x4*)(vTo + ((size_t)(b * 16 + h) * 64 + dk) * 1024 + s) = o;
      } else {
        ushort* op = proj == 0 ? qo : ko;
#pragma unroll
        for (int j = 0; j < 4; ++j)
          op[((size_t)(b * 16 + h) * 1024 + s + j) * 64 + dk] = f2bf(vv[j]);
      }
    }
  }
}

// ---------------- fused attention (double-buffered LDS K/V, cached flush) ----
// 2048 blocks (XCD-swizzled); 4 waves x 16 q-rows (lane lr = q-row).
// 16 groups of 64 kv, K/V double-buffered in LDS: stage(g+1) issued BEFORE
// compute(g); the single end-of-group __syncthreads drains it after a full
// compute phase (stage latency hidden). Per group: QK^T (4 frags) -> 2 slices
// of 32 kv {exp->p_q; scores->s_st; lgkmcnt; CACHED full-128B-line flush;
// PV 4 MFMA}. att values bit-identical to R12.
__global__ __launch_bounds__(256) void attn_kernel(const ushort* __restrict__ qg, const ushort* __restrict__ kg,
                                                   const ushort* __restrict__ vT, float* __restrict__ att,
                                                   ushort* __restrict__ heads) {
  const int bid = blockIdx.x;                 // 2048
  const int swz = (bid & 7) * 256 + (bid >> 3);
  const int qt = swz & 15, bh = swz >> 4;
  const int t = threadIdx.x, w = t >> 6, l = t & 63;
  const int lg = l >> 4, lr = l & 15;
  __shared__ ushort Ks[2][64 * 64];       // 16 KB, chunk-swizzled rows (128B)
  __shared__ ushort Vs[2][64 * 64];       // 16 KB, chunk-swizzled rows (128B)
  __shared__ ushort p_q[4][16][40];       // 5 KB, P slice (32 kv), per-wave reuse
  __shared__ float s_st[4][16][40];       // 10 KB, score slice (32 kv), reuse

  const ushort* qb = qg + (size_t)bh * 65536;
  const ushort* kb = kg + (size_t)bh * 65536;
  const ushort* vb = vT + (size_t)bh * 65536;
  const int qrow0 = qt * 64 + w * 16;

  const bf16x8 qf0 = *(const bf16x8*)(qb + (qrow0 + lr) * 64 + lg * 8);
  const bf16x8 qf1 = *(const bf16x8*)(qb + (qrow0 + lr) * 64 + 32 + lg * 8);

  const int krow = l >> 3, kch = l & 7;         // stage: 8 rows x 8 chunks(16B)/call
  const int frow = l >> 3, fcol = (l & 7) * 4;  // flush: 8 rows x 128B per instr

  const float C2 = 0.125f * 1.44269504f;   // 1/sqrt(64) in exp2 domain
  f32x4 oacc[4] = {};
  float lsum = 0.f;
  float* attw = att + ((size_t)bh * 1024 + qrow0) * 1024;

  // stage one 64-kv group into buffer bufi: K rows are kv, V rows are dk.
  // source chunk pre-swizzled (c ^ row&7) so linear LDS holds swizzled rows.
#define ATTN_STAGE(bufi, gi)                                                      \
  do {                                                                            \
    const int kv0s = (gi) * 64;                                                   \
    _Pragma("unroll")                                                             \
    for (int c2 = 0; c2 < 2; ++c2) {                                              \
      const int call = w * 2 + c2;                                                \
      const int rr = call * 8 + krow;                                             \
      gload_lds16(kb + (size_t)(kv0s + rr) * 64 + ((kch ^ (rr & 7)) * 8),         \
                  &Ks[bufi][call * 512]);                                         \
      gload_lds16(vb + (size_t)rr * 1024 + kv0s + ((kch ^ (rr & 7)) * 8),         \
                  &Vs[bufi][call * 512]);                                         \
    }                                                                             \
  } while (0)

  ATTN_STAGE(0, 0);
  __syncthreads();
  for (int g = 0; g < 16; ++g) {
    const int kv0 = g * 64;
    const int buf = g & 1;
    if (g < 15) ATTN_STAGE(buf ^ 1, g + 1);   // issue early; lands under compute
    // QK^T from LDS: sf[f][j] = S[q=lr][kv = kv0 + f*16 + lg*4 + j]
    f32x4 sf[4];
#pragma unroll
    for (int f = 0; f < 4; ++f) {
      const int r = f * 16 + lr;
      const bf16x8 kf0 = *(const bf16x8*)(&Ks[buf][r * 64 + ((lg ^ (r & 7)) * 8)]);
      const bf16x8 kf1 = *(const bf16x8*)(&Ks[buf][r * 64 + (((4 + lg) ^ (r & 7)) * 8)]);
      f32x4 s = {};
      s = MFMA16(kf0, qf0, s);
      s = MFMA16(kf1, qf1, s);
      sf[f] = s;
    }
    // 2 slices of 32 kv: exp/pack + score-stage -> cached line flush + PV
#pragma unroll
    for (int s = 0; s < 2; ++s) {
#pragma unroll
      for (int fi = 0; fi < 2; ++fi) {
        const int f = 2 * s + fi;
        u16x4 pk;
#pragma unroll
        for (int j = 0; j < 4; ++j) {
          const float p = exp2f(sf[f][j] * C2);
          lsum += p;
          pk[j] = f2bf(p);
        }
        *(u16x4*)(&p_q[w][lr][fi * 16 + lg * 4]) = pk;
        *(f32x4*)(&s_st[w][lr][fi * 16 + lg * 4]) = sf[f];
      }
      // per-wave LDS region; DS ops wave-program-order; wait for writes
      asm volatile("s_waitcnt lgkmcnt(0)" ::: "memory");
      __builtin_amdgcn_sched_barrier(0);
      const bf16x8 pa = *(const bf16x8*)(&p_q[w][lr][lg * 8]);
      // flush this slice: CACHED (L2 write-combining, fast barrier ack),
      // 2 instrs x 8 rows x fully-covered 128B aligned lines
#pragma unroll
      for (int i = 0; i < 2; ++i) {
        const int r = i * 8 + frow;
        const f32x4 fv = *(const f32x4*)(&s_st[w][r][fcol]);
        *(f32x4*)(attw + (size_t)r * 1024 + kv0 + s * 32 + fcol) = fv;
      }
      // PV for this slice (LDS/reg only)
#pragma unroll
      for (int nt = 0; nt < 4; ++nt) {
        const int r = nt * 16 + lr;
        const bf16x8 vf = *(const bf16x8*)(&Vs[buf][r * 64 + (((s * 4 + lg) ^ (r & 7)) * 8)]);
        oacc[nt] = MFMA16(pa, vf, oacc[nt]);
      }
    }
    __syncthreads();   // all waves done reading buf; stage(buf^1) drained (full compute phase elapsed)
  }
#undef ATTN_STAGE
  // row sums: reduce lane partials across lg groups
  lsum += __shfl_xor(lsum, 16, 64);
  lsum += __shfl_xor(lsum, 32, 64);
  float rdiv[4];
#pragma unroll
  for (int j = 0; j < 4; ++j) rdiv[j] = 1.f / __shfl(lsum, lg * 4 + j, 16);
  const int b = bh >> 4, h = bh & 15;
#pragma unroll
  for (int nt = 0; nt < 4; ++nt)
#pragma unroll
    for (int j = 0; j < 4; ++j)
      __builtin_nontemporal_store(f2bf(oacc[nt][j] * rdiv[j]),
          heads + (size_t)(b * 1024 + qrow0 + lg * 4 + j) * 1024 + h * 64 + nt * 16 + lr);
}

// ---------------- output GEMM: z_out = relu(heads @ Wo + bo) ----------------
__global__ __launch_bounds__(256) void gemm_out(const ushort* __restrict__ z, const ushort* __restrict__ Wop,
                                                const float* __restrict__ bo, float* __restrict__ out) {
  __shared__ float red[2][16][64];
  const int t = threadIdx.x, w = t >> 6, l = t & 63, lg = l >> 4, lr = l & 15;
  const int wm = w & 1, kh = w >> 1;
  const int m0 = blockIdx.x * 32 + wm * 16;
  f32x4 acc[4] = {};
  for (int kk = kh * 16; kk < kh * 16 + 16; ++kk) {
    bf16x8 af = *(const bf16x8*)(z + (size_t)(m0 + lr) * 1024 + kk * 32 + lg * 8);
#pragma unroll
    for (int nt = 0; nt < 4; ++nt) {
      bf16x8 bfr = *(const bf16x8*)(Wop + (size_t)(nt * 16 + lr) * 1024 + kk * 32 + lg * 8);
      acc[nt] = MFMA16(af, bfr, acc[nt]);
    }
  }
  if (kh == 1) {
#pragma unroll
    for (int nt = 0; nt < 4; ++nt)
#pragma unroll
      for (int j = 0; j < 4; ++j) red[wm][lg * 4 + j][nt * 16 + lr] = acc[nt][j];
  }
  __syncthreads();
  if (kh == 0) {
#pragma unroll
    for (int nt = 0; nt < 4; ++nt) {
      const int n = nt * 16 + lr;
      const float bb = bo[n];
#pragma unroll
      for (int j = 0; j < 4; ++j) {
        const int m = m0 + lg * 4 + j;
        float vv = acc[nt][j] + red[wm][lg * 4 + j][n] + bb;
        out[(size_t)m * 64 + n] = vv > 0.f ? vv : 0.f;
      }
    }
  }
}

// ---------------------------------------------------------------------------
extern "C" void kernel_launch(void* const* d_in, const int* in_sizes, int n_in,
                              void* d_out, int out_size, void* d_ws, size_t ws_size,
                              hipStream_t stream) {
  const float* x  = (const float*)d_in[0];
  const float* Wq = (const float*)d_in[1];
  const float* bq = (const float*)d_in[2];
  const float* Wk = (const float*)d_in[3];
  const float* bk = (const float*)d_in[4];
  const float* Wv = (const float*)d_in[5];
  const float* bv = (const float*)d_in[6];
  const float* Wo = (const float*)d_in[7];
  const float* bo = (const float*)d_in[8];
  float* out = (float*)d_out;            // z_out: 8*1024*64 = 524288 f32
  float* att = out + 524288;             // att:   8*16*1024*1024 f32

  // workspace layout (~92 MB)
  char* ws = (char*)d_ws;
  size_t off = 0;
  ushort* xb  = (ushort*)(ws + off); off += (size_t)8192 * 1024 * 2;
  ushort* Wp  = (ushort*)(ws + off); off += (size_t)3072 * 1024 * 2;
  ushort* Wop = (ushort*)(ws + off); off += (size_t)64 * 1024 * 2;
  float* bqkv = (float*)(ws + off);  off += (size_t)3072 * 4;
  ushort* q   = (ushort*)(ws + off); off += (size_t)128 * 1024 * 64 * 2;
  ushort* k   = (ushort*)(ws + off); off += (size_t)128 * 1024 * 64 * 2;
  ushort* vT  = (ushort*)(ws + off); off += (size_t)128 * 64 * 1024 * 2;
  ushort* hds = (ushort*)(ws + off); off += (size_t)8192 * 1024 * 2;
  (void)ws_size; (void)in_sizes; (void)n_in; (void)out_size;

  pack_all<<<dim3(20749), dim3(256), 0, stream>>>(x, Wq, Wk, Wv, Wo, bq, bk, bv,
                                                  xb, Wp, Wop, bqkv);
  gemm_qkv<<<dim3(1536), dim3(256), 0, stream>>>(xb, Wp, bqkv, q, k, vT);
  attn_kernel<<<dim3(2048), dim3(256), 0, stream>>>(q, k, vT, att, hds);
  gemm_out<<<dim3(256), dim3(256), 0, stream>>>(hds, Wop, bo, out);
}

// Round 14
// 240.408 us; speedup vs baseline: 1.2630x; 1.2630x over previous
//
#include <hip/hip_runtime.h>

// ---------------------------------------------------------------------------
// AttentionMultiHead: x[8,1024,1024] f32, per-head Wq/Wk/Wv[16,1024,64]+bias,
// Wo[1024,64]+bo. Outputs: z_out[8,1024,64] f32, att[8,16,1024,1024] f32 (raw).
//
// Ledger: R12 = 229.1us (attn ~120, gemm ~55, packs ~25, out ~8).
// R13 (+74.5 REGRESSION) bundled (a) 64-kv double-buffered staging with
// (b) nt->cached flush. (b) reverted a CONFIRMED win (R7: nt = -58us via L2
// pollution - 536MB stream evicts K/vT staging lines regardless of line
// coverage). R14: revert (b) only -> nt flush (R12 geometry), KEEP (a).
// Single-variable read: <=230 means (b) was sole culprit ((a) neutral/good);
// >=260 means (a) also hurts -> revert attn to exact R12 next.
// ---------------------------------------------------------------------------

typedef __bf16 bf16x8 __attribute__((ext_vector_type(8)));
typedef float f32x4 __attribute__((ext_vector_type(4)));
typedef unsigned short u16x8 __attribute__((ext_vector_type(8)));
typedef unsigned short u16x4 __attribute__((ext_vector_type(4)));

typedef __attribute__((address_space(1))) unsigned int as1_u32;
typedef __attribute__((address_space(3))) unsigned int as3_u32;

#define MFMA16(a, b, c) __builtin_amdgcn_mfma_f32_16x16x32_bf16(a, b, c, 0, 0, 0)

__device__ __forceinline__ void gload_lds16(const void* g, void* l) {
  __builtin_amdgcn_global_load_lds((const as1_u32*)g, (as3_u32*)l, 16, 0, 0);
}

__device__ __forceinline__ unsigned short f2bf(float f) {
  union { float f; unsigned u; } a; a.f = f;
  unsigned r = a.u + 0x7FFFu + ((a.u >> 16) & 1u);  // RNE
  return (unsigned short)(r >> 16);
}

// ---------------- fused pack kernel ----------------
__global__ __launch_bounds__(256) void pack_all(const float* __restrict__ x, const float* __restrict__ Wq,
                                                const float* __restrict__ Wk, const float* __restrict__ Wv,
                                                const float* __restrict__ Wo, const float* __restrict__ bq,
                                                const float* __restrict__ bk, const float* __restrict__ bv,
                                                ushort* __restrict__ xb, ushort* __restrict__ Wp,
                                                ushort* __restrict__ Wop, float* __restrict__ bqkv) {
  const int bid = blockIdx.x;
  if (bid < 8192) {
    const size_t i = ((size_t)bid * 256 + threadIdx.x) * 4;
    const float4 v = *(const float4*)(x + i);
    u16x4 o; o[0] = f2bf(v.x); o[1] = f2bf(v.y); o[2] = f2bf(v.z); o[3] = f2bf(v.w);
    *(u16x4*)(xb + i) = o;
  } else if (bid < 20480) {
    const int b2 = bid - 8192;
    const int swz = (b2 & 7) * 1536 + (b2 >> 3);
    const int o = swz * 256 + threadIdx.x;  // 0 .. 3072*1024
    const int n = o >> 10, d = o & 1023;
    const int proj = n >> 10, hk = n & 1023;
    const float* W = proj == 0 ? Wq : (proj == 1 ? Wk : Wv);
    const int h = hk >> 6, kk = hk & 63;
    Wp[o] = f2bf(W[((size_t)h * 1024 + d) * 64 + kk]);
  } else {
    const int idx = (bid - 20480) * 256 + threadIdx.x;
    if (idx < 65536) {
      const int n = idx >> 10, c = idx & 1023;   // Wop[n][c] = Wo[c][n]
      Wop[idx] = f2bf(Wo[c * 64 + n]);
    } else if (idx < 65536 + 3072) {
      const int n = idx - 65536;
      const int proj = n >> 10;
      const float* bb = proj == 0 ? bq : (proj == 1 ? bk : bv);
      bqkv[n] = bb[n & 1023];
    }
  }
}

// ---------------- QKV projection GEMM (R3 structure) ----------------
__global__ __launch_bounds__(256) void gemm_qkv(const ushort* __restrict__ xb, const ushort* __restrict__ Wp,
                                                const float* __restrict__ bqkv, ushort* __restrict__ qo,
                                                ushort* __restrict__ ko, ushort* __restrict__ vTo) {
  __shared__ ushort As[128 * 32], Bs[128 * 32];
  const int bid = blockIdx.x;                 // 1536 blocks
  const int swz = (bid & 7) * 192 + (bid >> 3);
  const int by = swz / 24, bx = swz - by * 24;
  const int t = threadIdx.x, w = t >> 6, l = t & 63, lg = l >> 4, lr = l & 15;
  const int m0 = by * 128, n0 = bx * 128;
  const int wm = w >> 1, wn = w & 1;
  const int srow = l >> 2, sslot = l & 3;
  f32x4 acc[4][4] = {};
  for (int kt = 0; kt < 32; ++kt) {
    __syncthreads();
#pragma unroll
    for (int c = 0; c < 2; ++c) {
      const int cc = w * 2 + c;              // 0..7, 1KB chunk per wave-call
      const int row = cc * 16 + srow;        // LDS linear == row*64B + slot*16B
      gload_lds16(xb + (size_t)(m0 + row) * 1024 + kt * 32 + sslot * 8, &As[cc * 512]);
      gload_lds16(Wp + (size_t)(n0 + row) * 1024 + kt * 32 + sslot * 8, &Bs[cc * 512]);
    }
    __syncthreads();
    bf16x8 af[4], bfr[4];
#pragma unroll
    for (int mt = 0; mt < 4; ++mt)
      af[mt] = *(const bf16x8*)(&As[(wm * 64 + mt * 16 + lr) * 32 + lg * 8]);
#pragma unroll
    for (int nt = 0; nt < 4; ++nt)
      bfr[nt] = *(const bf16x8*)(&Bs[(wn * 64 + nt * 16 + lr) * 32 + lg * 8]);
#pragma unroll
    for (int mt = 0; mt < 4; ++mt)
#pragma unroll
      for (int nt = 0; nt < 4; ++nt)
        acc[mt][nt] = MFMA16(af[mt], bfr[nt], acc[mt][nt]);
  }
  // epilogue: bias + relu -> bf16. proj uniform across the wave (16-aligned n-chunks).
#pragma unroll
  for (int nt = 0; nt < 4; ++nt) {
    const int n = n0 + wn * 64 + nt * 16 + lr;
    const float bias = bqkv[n];
    const int proj = n >> 10, h = (n >> 6) & 15, dk = n & 63;
#pragma unroll
    for (int mt = 0; mt < 4; ++mt) {
      const int mb = m0 + wm * 64 + mt * 16 + lg * 4;  // j-quad base, same b & 4-aligned s
      const int b = mb >> 10, s = mb & 1023;
      float vv[4];
#pragma unroll
      for (int j = 0; j < 4; ++j) {
        float a = acc[mt][nt][j] + bias;
        vv[j] = a > 0.f ? a : 0.f;
      }
      if (proj == 2) {
        u16x4 o; o[0] = f2bf(vv[0]); o[1] = f2bf(vv[1]); o[2] = f2bf(vv[2]); o[3] = f2bf(vv[3]);
        *(u16x4*)(vTo + ((size_t)(b * 16 + h) * 64 + dk) * 1024 + s) = o;
      } else {
        ushort* op = proj == 0 ? qo : ko;
#pragma unroll
        for (int j = 0; j < 4; ++j)
          op[((size_t)(b * 16 + h) * 1024 + s + j) * 64 + dk] = f2bf(vv[j]);
      }
    }
  }
}

// ---------------- fused attention (double-buffered LDS K/V, nt line flush) ---
// 2048 blocks (XCD-swizzled); 4 waves x 16 q-rows (lane lr = q-row).
// 16 groups of 64 kv, K/V double-buffered: stage(g+1) issued BEFORE compute(g).
// Per group: QK^T (4 frags) -> 2 slices of 32 kv {exp->p_q; scores->s_st;
// lgkmcnt; NT full-128B-line flush (R12 geometry, confirmed -49us; nt
// confirmed -58us R7); PV 4 MFMA}. Values bit-identical to R12/R13.
__global__ __launch_bounds__(256) void attn_kernel(const ushort* __restrict__ qg, const ushort* __restrict__ kg,
                                                   const ushort* __restrict__ vT, float* __restrict__ att,
                                                   ushort* __restrict__ heads) {
  const int bid = blockIdx.x;                 // 2048
  const int swz = (bid & 7) * 256 + (bid >> 3);
  const int qt = swz & 15, bh = swz >> 4;
  const int t = threadIdx.x, w = t >> 6, l = t & 63;
  const int lg = l >> 4, lr = l & 15;
  __shared__ ushort Ks[2][64 * 64];       // 16 KB, chunk-swizzled rows (128B)
  __shared__ ushort Vs[2][64 * 64];       // 16 KB, chunk-swizzled rows (128B)
  __shared__ ushort p_q[4][16][40];       // 5 KB, P slice (32 kv), per-wave reuse
  __shared__ float s_st[4][16][40];       // 10 KB, score slice (32 kv), reuse

  const ushort* qb = qg + (size_t)bh * 65536;
  const ushort* kb = kg + (size_t)bh * 65536;
  const ushort* vb = vT + (size_t)bh * 65536;
  const int qrow0 = qt * 64 + w * 16;

  const bf16x8 qf0 = *(const bf16x8*)(qb + (qrow0 + lr) * 64 + lg * 8);
  const bf16x8 qf1 = *(const bf16x8*)(qb + (qrow0 + lr) * 64 + 32 + lg * 8);

  const int krow = l >> 3, kch = l & 7;         // stage: 8 rows x 8 chunks(16B)/call
  const int frow = l >> 3, fcol = (l & 7) * 4;  // flush: 8 rows x 128B per instr

  const float C2 = 0.125f * 1.44269504f;   // 1/sqrt(64) in exp2 domain
  f32x4 oacc[4] = {};
  float lsum = 0.f;
  float* attw = att + ((size_t)bh * 1024 + qrow0) * 1024;

#define ATTN_STAGE(bufi, gi)                                                      \
  do {                                                                            \
    const int kv0s = (gi) * 64;                                                   \
    _Pragma("unroll")                                                             \
    for (int c2 = 0; c2 < 2; ++c2) {                                              \
      const int call = w * 2 + c2;                                                \
      const int rr = call * 8 + krow;                                             \
      gload_lds16(kb + (size_t)(kv0s + rr) * 64 + ((kch ^ (rr & 7)) * 8),         \
                  &Ks[bufi][call * 512]);                                         \
      gload_lds16(vb + (size_t)rr * 1024 + kv0s + ((kch ^ (rr & 7)) * 8),         \
                  &Vs[bufi][call * 512]);                                         \
    }                                                                             \
  } while (0)

  ATTN_STAGE(0, 0);
  __syncthreads();
  for (int g = 0; g < 16; ++g) {
    const int kv0 = g * 64;
    const int buf = g & 1;
    if (g < 15) ATTN_STAGE(buf ^ 1, g + 1);   // issue early; lands under compute
    // QK^T from LDS: sf[f][j] = S[q=lr][kv = kv0 + f*16 + lg*4 + j]
    f32x4 sf[4];
#pragma unroll
    for (int f = 0; f < 4; ++f) {
      const int r = f * 16 + lr;
      const bf16x8 kf0 = *(const bf16x8*)(&Ks[buf][r * 64 + ((lg ^ (r & 7)) * 8)]);
      const bf16x8 kf1 = *(const bf16x8*)(&Ks[buf][r * 64 + (((4 + lg) ^ (r & 7)) * 8)]);
      f32x4 s = {};
      s = MFMA16(kf0, qf0, s);
      s = MFMA16(kf1, qf1, s);
      sf[f] = s;
    }
    // 2 slices of 32 kv: exp/pack + score-stage -> nt line flush + PV
#pragma unroll
    for (int s = 0; s < 2; ++s) {
#pragma unroll
      for (int fi = 0; fi < 2; ++fi) {
        const int f = 2 * s + fi;
        u16x4 pk;
#pragma unroll
        for (int j = 0; j < 4; ++j) {
          const float p = exp2f(sf[f][j] * C2);
          lsum += p;
          pk[j] = f2bf(p);
        }
        *(u16x4*)(&p_q[w][lr][fi * 16 + lg * 4]) = pk;
        *(f32x4*)(&s_st[w][lr][fi * 16 + lg * 4]) = sf[f];
      }
      // per-wave LDS region; DS ops wave-program-order; wait for writes
      asm volatile("s_waitcnt lgkmcnt(0)" ::: "memory");
      __builtin_amdgcn_sched_barrier(0);
      const bf16x8 pa = *(const bf16x8*)(&p_q[w][lr][lg * 8]);
      // flush this slice: NT (no L2 pollution - R7), fully-covered 128B lines
#pragma unroll
      for (int i = 0; i < 2; ++i) {
        const int r = i * 8 + frow;
        const f32x4 fv = *(const f32x4*)(&s_st[w][r][fcol]);
        __builtin_nontemporal_store(fv,
            (f32x4*)(attw + (size_t)r * 1024 + kv0 + s * 32 + fcol));
      }
      // PV for this slice (LDS/reg only)
#pragma unroll
      for (int nt = 0; nt < 4; ++nt) {
        const int r = nt * 16 + lr;
        const bf16x8 vf = *(const bf16x8*)(&Vs[buf][r * 64 + (((s * 4 + lg) ^ (r & 7)) * 8)]);
        oacc[nt] = MFMA16(pa, vf, oacc[nt]);
      }
    }
    __syncthreads();   // all waves done reading buf; stage(buf^1) drained
  }
#undef ATTN_STAGE
  // row sums: reduce lane partials across lg groups
  lsum += __shfl_xor(lsum, 16, 64);
  lsum += __shfl_xor(lsum, 32, 64);
  float rdiv[4];
#pragma unroll
  for (int j = 0; j < 4; ++j) rdiv[j] = 1.f / __shfl(lsum, lg * 4 + j, 16);
  const int b = bh >> 4, h = bh & 15;
#pragma unroll
  for (int nt = 0; nt < 4; ++nt)
#pragma unroll
    for (int j = 0; j < 4; ++j)
      __builtin_nontemporal_store(f2bf(oacc[nt][j] * rdiv[j]),
          heads + (size_t)(b * 1024 + qrow0 + lg * 4 + j) * 1024 + h * 64 + nt * 16 + lr);
}

// ---------------- output GEMM: z_out = relu(heads @ Wo + bo) ----------------
__global__ __launch_bounds__(256) void gemm_out(const ushort* __restrict__ z, const ushort* __restrict__ Wop,
                                                const float* __restrict__ bo, float* __restrict__ out) {
  __shared__ float red[2][16][64];
  const int t = threadIdx.x, w = t >> 6, l = t & 63, lg = l >> 4, lr = l & 15;
  const int wm = w & 1, kh = w >> 1;
  const int m0 = blockIdx.x * 32 + wm * 16;
  f32x4 acc[4] = {};
  for (int kk = kh * 16; kk < kh * 16 + 16; ++kk) {
    bf16x8 af = *(const bf16x8*)(z + (size_t)(m0 + lr) * 1024 + kk * 32 + lg * 8);
#pragma unroll
    for (int nt = 0; nt < 4; ++nt) {
      bf16x8 bfr = *(const bf16x8*)(Wop + (size_t)(nt * 16 + lr) * 1024 + kk * 32 + lg * 8);
      acc[nt] = MFMA16(af, bfr, acc[nt]);
    }
  }
  if (kh == 1) {
#pragma unroll
    for (int nt = 0; nt < 4; ++nt)
#pragma unroll
      for (int j = 0; j < 4; ++j) red[wm][lg * 4 + j][nt * 16 + lr] = acc[nt][j];
  }
  __syncthreads();
  if (kh == 0) {
#pragma unroll
    for (int nt = 0; nt < 4; ++nt) {
      const int n = nt * 16 + lr;
      const float bb = bo[n];
#pragma unroll
      for (int j = 0; j < 4; ++j) {
        const int m = m0 + lg * 4 + j;
        float vv = acc[nt][j] + red[wm][lg * 4 + j][n] + bb;
        out[(size_t)m * 64 + n] = vv > 0.f ? vv : 0.f;
      }
    }
  }
}

// ---------------------------------------------------------------------------
extern "C" void kernel_launch(void* const* d_in, const int* in_sizes, int n_in,
                              void* d_out, int out_size, void* d_ws, size_t ws_size,
                              hipStream_t stream) {
  const float* x  = (const float*)d_in[0];
  const float* Wq = (const float*)d_in[1];
  const float* bq = (const float*)d_in[2];
  const float* Wk = (const float*)d_in[3];
  const float* bk = (const float*)d_in[4];
  const float* Wv = (const float*)d_in[5];
  const float* bv = (const float*)d_in[6];
  const float* Wo = (const float*)d_in[7];
  const float* bo = (const float*)d_in[8];
  float* out = (float*)d_out;            // z_out: 8*1024*64 = 524288 f32
  float* att = out + 524288;             // att:   8*16*1024*1024 f32

  // workspace layout (~92 MB)
  char* ws = (char*)d_ws;
  size_t off = 0;
  ushort* xb  = (ushort*)(ws + off); off += (size_t)8192 * 1024 * 2;
  ushort* Wp  = (ushort*)(ws + off); off += (size_t)3072 * 1024 * 2;
  ushort* Wop = (ushort*)(ws + off); off += (size_t)64 * 1024 * 2;
  float* bqkv = (float*)(ws + off);  off += (size_t)3072 * 4;
  ushort* q   = (ushort*)(ws + off); off += (size_t)128 * 1024 * 64 * 2;
  ushort* k   = (ushort*)(ws + off); off += (size_t)128 * 1024 * 64 * 2;
  ushort* vT  = (ushort*)(ws + off); off += (size_t)128 * 64 * 1024 * 2;
  ushort* hds = (ushort*)(ws + off); off += (size_t)8192 * 1024 * 2;
  (void)ws_size; (void)in_sizes; (void)n_in; (void)out_size;

  pack_all<<<dim3(20749), dim3(256), 0, stream>>>(x, Wq, Wk, Wv, Wo, bq, bk, bv,
                                                  xb, Wp, Wop, bqkv);
  gemm_qkv<<<dim3(1536), dim3(256), 0, stream>>>(xb, Wp, bqkv, q, k, vT);
  attn_kernel<<<dim3(2048), dim3(256), 0, stream>>>(q, k, vT, att, hds);
  gemm_out<<<dim3(256), dim3(256), 0, stream>>>(hds, Wop, bo, out);
}

// Round 15
// 228.268 us; speedup vs baseline: 1.3301x; 1.0532x over previous
//
#include <hip/hip_runtime.h>

// ---------------------------------------------------------------------------
// AttentionMultiHead: x[8,1024,1024] f32, per-head Wq/Wk/Wv[16,1024,64]+bias,
// Wo[1024,64]+bo. Outputs: z_out[8,1024,64] f32, att[8,16,1024,1024] f32 (raw).
//
// Ledger: best = R12 229.1us (attn ~120, gemm ~55, packs ~25, out ~8).
// R13: cached flush = -63us mistake (L2 pollution; R7's nt win stands).
// R14: 64-kv double-buffered staging = +11 vs R12 (less compute shadow per
// barrier for store retirement). R15: attn reverted EXACTLY to R12
// (single-buffered 128-kv groups, nt full-128B-line flush). One new variable:
// gemm_qkv XCD swizzle flipped to by-inner (A-panels 2MB L2-resident per XCD,
// B-panel 256KB hot across its 8-block group; was bx-fastest = 6MB B thrash).
// ---------------------------------------------------------------------------

typedef __bf16 bf16x8 __attribute__((ext_vector_type(8)));
typedef float f32x4 __attribute__((ext_vector_type(4)));
typedef unsigned short u16x8 __attribute__((ext_vector_type(8)));
typedef unsigned short u16x4 __attribute__((ext_vector_type(4)));

typedef __attribute__((address_space(1))) unsigned int as1_u32;
typedef __attribute__((address_space(3))) unsigned int as3_u32;

#define MFMA16(a, b, c) __builtin_amdgcn_mfma_f32_16x16x32_bf16(a, b, c, 0, 0, 0)

__device__ __forceinline__ void gload_lds16(const void* g, void* l) {
  __builtin_amdgcn_global_load_lds((const as1_u32*)g, (as3_u32*)l, 16, 0, 0);
}

__device__ __forceinline__ unsigned short f2bf(float f) {
  union { float f; unsigned u; } a; a.f = f;
  unsigned r = a.u + 0x7FFFu + ((a.u >> 16) & 1u);  // RNE
  return (unsigned short)(r >> 16);
}

// ---------------- fused pack kernel ----------------
__global__ __launch_bounds__(256) void pack_all(const float* __restrict__ x, const float* __restrict__ Wq,
                                                const float* __restrict__ Wk, const float* __restrict__ Wv,
                                                const float* __restrict__ Wo, const float* __restrict__ bq,
                                                const float* __restrict__ bk, const float* __restrict__ bv,
                                                ushort* __restrict__ xb, ushort* __restrict__ Wp,
                                                ushort* __restrict__ Wop, float* __restrict__ bqkv) {
  const int bid = blockIdx.x;
  if (bid < 8192) {
    const size_t i = ((size_t)bid * 256 + threadIdx.x) * 4;
    const float4 v = *(const float4*)(x + i);
    u16x4 o; o[0] = f2bf(v.x); o[1] = f2bf(v.y); o[2] = f2bf(v.z); o[3] = f2bf(v.w);
    *(u16x4*)(xb + i) = o;
  } else if (bid < 20480) {
    const int b2 = bid - 8192;
    const int swz = (b2 & 7) * 1536 + (b2 >> 3);
    const int o = swz * 256 + threadIdx.x;  // 0 .. 3072*1024
    const int n = o >> 10, d = o & 1023;
    const int proj = n >> 10, hk = n & 1023;
    const float* W = proj == 0 ? Wq : (proj == 1 ? Wk : Wv);
    const int h = hk >> 6, kk = hk & 63;
    Wp[o] = f2bf(W[((size_t)h * 1024 + d) * 64 + kk]);
  } else {
    const int idx = (bid - 20480) * 256 + threadIdx.x;
    if (idx < 65536) {
      const int n = idx >> 10, c = idx & 1023;   // Wop[n][c] = Wo[c][n]
      Wop[idx] = f2bf(Wo[c * 64 + n]);
    } else if (idx < 65536 + 3072) {
      const int n = idx - 65536;
      const int proj = n >> 10;
      const float* bb = proj == 0 ? bq : (proj == 1 ? bk : bv);
      bqkv[n] = bb[n & 1023];
    }
  }
}

// ---------------- QKV projection GEMM (R3 structure, by-inner XCD swizzle) ---
__global__ __launch_bounds__(256) void gemm_qkv(const ushort* __restrict__ xb, const ushort* __restrict__ Wp,
                                                const float* __restrict__ bqkv, ushort* __restrict__ qo,
                                                ushort* __restrict__ ko, ushort* __restrict__ vTo) {
  __shared__ ushort As[128 * 32], Bs[128 * 32];
  const int bid = blockIdx.x;                 // 1536 blocks
  // by-inner XCD swizzle: xcd owns by in [xcd*8, xcd*8+8) x all 24 bx;
  // within an XCD, by varies fastest -> 2MB A-panel set L2-resident,
  // each 256KB B-panel hot across its 8-block group. Bijective.
  const int xcd = bid & 7, idx = bid >> 3;
  const int bx = idx >> 3, by = xcd * 8 + (idx & 7);
  const int t = threadIdx.x, w = t >> 6, l = t & 63, lg = l >> 4, lr = l & 15;
  const int m0 = by * 128, n0 = bx * 128;
  const int wm = w >> 1, wn = w & 1;
  const int srow = l >> 2, sslot = l & 3;
  f32x4 acc[4][4] = {};
  for (int kt = 0; kt < 32; ++kt) {
    __syncthreads();
#pragma unroll
    for (int c = 0; c < 2; ++c) {
      const int cc = w * 2 + c;              // 0..7, 1KB chunk per wave-call
      const int row = cc * 16 + srow;        // LDS linear == row*64B + slot*16B
      gload_lds16(xb + (size_t)(m0 + row) * 1024 + kt * 32 + sslot * 8, &As[cc * 512]);
      gload_lds16(Wp + (size_t)(n0 + row) * 1024 + kt * 32 + sslot * 8, &Bs[cc * 512]);
    }
    __syncthreads();
    bf16x8 af[4], bfr[4];
#pragma unroll
    for (int mt = 0; mt < 4; ++mt)
      af[mt] = *(const bf16x8*)(&As[(wm * 64 + mt * 16 + lr) * 32 + lg * 8]);
#pragma unroll
    for (int nt = 0; nt < 4; ++nt)
      bfr[nt] = *(const bf16x8*)(&Bs[(wn * 64 + nt * 16 + lr) * 32 + lg * 8]);
#pragma unroll
    for (int mt = 0; mt < 4; ++mt)
#pragma unroll
      for (int nt = 0; nt < 4; ++nt)
        acc[mt][nt] = MFMA16(af[mt], bfr[nt], acc[mt][nt]);
  }
  // epilogue: bias + relu -> bf16. proj uniform across the wave (16-aligned n-chunks).
#pragma unroll
  for (int nt = 0; nt < 4; ++nt) {
    const int n = n0 + wn * 64 + nt * 16 + lr;
    const float bias = bqkv[n];
    const int proj = n >> 10, h = (n >> 6) & 15, dk = n & 63;
#pragma unroll
    for (int mt = 0; mt < 4; ++mt) {
      const int mb = m0 + wm * 64 + mt * 16 + lg * 4;  // j-quad base, same b & 4-aligned s
      const int b = mb >> 10, s = mb & 1023;
      float vv[4];
#pragma unroll
      for (int j = 0; j < 4; ++j) {
        float a = acc[mt][nt][j] + bias;
        vv[j] = a > 0.f ? a : 0.f;
      }
      if (proj == 2) {
        u16x4 o; o[0] = f2bf(vv[0]); o[1] = f2bf(vv[1]); o[2] = f2bf(vv[2]); o[3] = f2bf(vv[3]);
        *(u16x4*)(vTo + ((size_t)(b * 16 + h) * 64 + dk) * 1024 + s) = o;
      } else {
        ushort* op = proj == 0 ? qo : ko;
#pragma unroll
        for (int j = 0; j < 4; ++j)
          op[((size_t)(b * 16 + h) * 1024 + s + j) * 64 + dk] = f2bf(vv[j]);
      }
    }
  }
}

// ---------------- fused attention (EXACT R12: LDS K/V, nt 128B-line flush) ---
// 2048 blocks (XCD-swizzled); 4 waves x 16 q-rows (lane lr = q-row).
// Per 128-kv group: stage K,V to LDS (coalesced gload_lds, chunk-XOR source
// pre-swizzle); QK^T (swapped) for all 8 frags; then 4 s-slices of 32 kv:
// {exp->p_q + scores->s_st; lgkmcnt; flush s_st as 8-row x 128B fully-covered
// NT line-writes; PV 4 MFMA (retire shadow)}.
__global__ __launch_bounds__(256) void attn_kernel(const ushort* __restrict__ qg, const ushort* __restrict__ kg,
                                                   const ushort* __restrict__ vT, float* __restrict__ att,
                                                   ushort* __restrict__ heads) {
  const int bid = blockIdx.x;                 // 2048
  const int swz = (bid & 7) * 256 + (bid >> 3);
  const int qt = swz & 15, bh = swz >> 4;
  const int t = threadIdx.x, w = t >> 6, l = t & 63;
  const int lg = l >> 4, lr = l & 15;
  __shared__ ushort Ks[128 * 64];         // 16 KB, chunk-swizzled rows
  __shared__ ushort Vs[64 * 128];         // 16 KB, chunk-swizzled rows
  __shared__ ushort p_q[4][16][40];       // 5 KB, P quarter (32 kv), reused
  __shared__ float s_st[4][16][40];       // 10 KB, score quarter (32 kv), reused

  const ushort* qb = qg + (size_t)bh * 65536;
  const ushort* kb = kg + (size_t)bh * 65536;
  const ushort* vb = vT + (size_t)bh * 65536;
  const int qrow0 = qt * 64 + w * 16;

  const bf16x8 qf0 = *(const bf16x8*)(qb + (qrow0 + lr) * 64 + lg * 8);
  const bf16x8 qf1 = *(const bf16x8*)(qb + (qrow0 + lr) * 64 + 32 + lg * 8);

  const int krow = l >> 3, kch = l & 7;    // K: 8 rows x 8 chunks(16B)
  const int vrow = l >> 4, vch = l & 15;   // V: 4 rows x 16 chunks(16B)
  const int frow = l >> 3, fcol = (l & 7) * 4;  // flush: 8 rows x 128B per instr

  const float C2 = 0.125f * 1.44269504f;   // 1/sqrt(64) in exp2 domain
  f32x4 oacc[4] = {};
  float lsum = 0.f;
  float* attw = att + ((size_t)bh * 1024 + qrow0) * 1024;

  for (int g = 0; g < 8; ++g) {
    const int kv0 = g * 128;
    __syncthreads();   // all waves done reading previous group's tiles
#pragma unroll
    for (int c2 = 0; c2 < 4; ++c2) {
      const int call = w * 4 + c2;
      const int r = call * 8 + krow;       // K local row 0..127
      gload_lds16(kb + (size_t)(kv0 + r) * 64 + ((kch ^ (r & 7)) * 8), &Ks[call * 512]);
      const int rv = call * 4 + vrow;      // V local row (dk) 0..63
      gload_lds16(vb + (size_t)rv * 1024 + kv0 + ((vch ^ (rv & 15)) * 8), &Vs[call * 512]);
    }
    __syncthreads();   // stage complete
    // QK^T from LDS: sf[f][j] = S[q=lr][kv = kv0 + f*16 + lg*4 + j]
    f32x4 sf[8];
#pragma unroll
    for (int f = 0; f < 8; ++f) {
      const int r = f * 16 + lr;
      const bf16x8 kf0 = *(const bf16x8*)(&Ks[r * 64 + ((lg ^ (r & 7)) * 8)]);
      const bf16x8 kf1 = *(const bf16x8*)(&Ks[r * 64 + (((4 + lg) ^ (r & 7)) * 8)]);
      f32x4 s = {};
      s = MFMA16(kf0, qf0, s);
      s = MFMA16(kf1, qf1, s);
      sf[f] = s;
    }
    // 4 slices of 32 kv: exp/pack + score-stage -> nt line flush + PV
#pragma unroll
    for (int s = 0; s < 4; ++s) {
#pragma unroll
      for (int fi = 0; fi < 2; ++fi) {
        const int f = 2 * s + fi;
        u16x4 pk;
#pragma unroll
        for (int j = 0; j < 4; ++j) {
          const float p = exp2f(sf[f][j] * C2);
          lsum += p;
          pk[j] = f2bf(p);
        }
        *(u16x4*)(&p_q[w][lr][fi * 16 + lg * 4]) = pk;
        *(f32x4*)(&s_st[w][lr][fi * 16 + lg * 4]) = sf[f];
      }
      // per-wave LDS region; DS ops wave-program-order; wait for writes
      asm volatile("s_waitcnt lgkmcnt(0)" ::: "memory");
      __builtin_amdgcn_sched_barrier(0);
      const bf16x8 pa = *(const bf16x8*)(&p_q[w][lr][lg * 8]);
      // flush this slice: 2 instrs x 8 rows x 128B fully-covered aligned lines
#pragma unroll
      for (int i = 0; i < 2; ++i) {
        const int r = i * 8 + frow;
        const f32x4 fv = *(const f32x4*)(&s_st[w][r][fcol]);
        __builtin_nontemporal_store(fv,
            (f32x4*)(attw + (size_t)r * 1024 + kv0 + s * 32 + fcol));
      }
      // PV for this slice (LDS/reg only -> store retire shadow)
#pragma unroll
      for (int nt = 0; nt < 4; ++nt) {
        const int r = nt * 16 + lr;
        const bf16x8 vf = *(const bf16x8*)(&Vs[r * 128 + (((s * 4 + lg) ^ lr) * 8)]);
        oacc[nt] = MFMA16(pa, vf, oacc[nt]);
      }
    }
  }
  // row sums: reduce lane partials across lg groups
  lsum += __shfl_xor(lsum, 16, 64);
  lsum += __shfl_xor(lsum, 32, 64);
  float rdiv[4];
#pragma unroll
  for (int j = 0; j < 4; ++j) rdiv[j] = 1.f / __shfl(lsum, lg * 4 + j, 16);
  const int b = bh >> 4, h = bh & 15;
#pragma unroll
  for (int nt = 0; nt < 4; ++nt)
#pragma unroll
    for (int j = 0; j < 4; ++j)
      __builtin_nontemporal_store(f2bf(oacc[nt][j] * rdiv[j]),
          heads + (size_t)(b * 1024 + qrow0 + lg * 4 + j) * 1024 + h * 64 + nt * 16 + lr);
}

// ---------------- output GEMM: z_out = relu(heads @ Wo + bo) ----------------
__global__ __launch_bounds__(256) void gemm_out(const ushort* __restrict__ z, const ushort* __restrict__ Wop,
                                                const float* __restrict__ bo, float* __restrict__ out) {
  __shared__ float red[2][16][64];
  const int t = threadIdx.x, w = t >> 6, l = t & 63, lg = l >> 4, lr = l & 15;
  const int wm = w & 1, kh = w >> 1;
  const int m0 = blockIdx.x * 32 + wm * 16;
  f32x4 acc[4] = {};
  for (int kk = kh * 16; kk < kh * 16 + 16; ++kk) {
    bf16x8 af = *(const bf16x8*)(z + (size_t)(m0 + lr) * 1024 + kk * 32 + lg * 8);
#pragma unroll
    for (int nt = 0; nt < 4; ++nt) {
      bf16x8 bfr = *(const bf16x8*)(Wop + (size_t)(nt * 16 + lr) * 1024 + kk * 32 + lg * 8);
      acc[nt] = MFMA16(af, bfr, acc[nt]);
    }
  }
  if (kh == 1) {
#pragma unroll
    for (int nt = 0; nt < 4; ++nt)
#pragma unroll
      for (int j = 0; j < 4; ++j) red[wm][lg * 4 + j][nt * 16 + lr] = acc[nt][j];
  }
  __syncthreads();
  if (kh == 0) {
#pragma unroll
    for (int nt = 0; nt < 4; ++nt) {
      const int n = nt * 16 + lr;
      const float bb = bo[n];
#pragma unroll
      for (int j = 0; j < 4; ++j) {
        const int m = m0 + lg * 4 + j;
        float vv = acc[nt][j] + red[wm][lg * 4 + j][n] + bb;
        out[(size_t)m * 64 + n] = vv > 0.f ? vv : 0.f;
      }
    }
  }
}

// ---------------------------------------------------------------------------
extern "C" void kernel_launch(void* const* d_in, const int* in_sizes, int n_in,
                              void* d_out, int out_size, void* d_ws, size_t ws_size,
                              hipStream_t stream) {
  const float* x  = (const float*)d_in[0];
  const float* Wq = (const float*)d_in[1];
  const float* bq = (const float*)d_in[2];
  const float* Wk = (const float*)d_in[3];
  const float* bk = (const float*)d_in[4];
  const float* Wv = (const float*)d_in[5];
  const float* bv = (const float*)d_in[6];
  const float* Wo = (const float*)d_in[7];
  const float* bo = (const float*)d_in[8];
  float* out = (float*)d_out;            // z_out: 8*1024*64 = 524288 f32
  float* att = out + 524288;             // att:   8*16*1024*1024 f32

  // workspace layout (~92 MB)
  char* ws = (char*)d_ws;
  size_t off = 0;
  ushort* xb  = (ushort*)(ws + off); off += (size_t)8192 * 1024 * 2;
  ushort* Wp  = (ushort*)(ws + off); off += (size_t)3072 * 1024 * 2;
  ushort* Wop = (ushort*)(ws + off); off += (size_t)64 * 1024 * 2;
  float* bqkv = (float*)(ws + off);  off += (size_t)3072 * 4;
  ushort* q   = (ushort*)(ws + off); off += (size_t)128 * 1024 * 64 * 2;
  ushort* k   = (ushort*)(ws + off); off += (size_t)128 * 1024 * 64 * 2;
  ushort* vT  = (ushort*)(ws + off); off += (size_t)128 * 64 * 1024 * 2;
  ushort* hds = (ushort*)(ws + off); off += (size_t)8192 * 1024 * 2;
  (void)ws_size; (void)in_sizes; (void)n_in; (void)out_size;

  pack_all<<<dim3(20749), dim3(256), 0, stream>>>(x, Wq, Wk, Wv, Wo, bq, bk, bv,
                                                  xb, Wp, Wop, bqkv);
  gemm_qkv<<<dim3(1536), dim3(256), 0, stream>>>(xb, Wp, bqkv, q, k, vT);
  attn_kernel<<<dim3(2048), dim3(256), 0, stream>>>(q, k, vT, att, hds);
  gemm_out<<<dim3(256), dim3(256), 0, stream>>>(hds, Wop, bo, out);
}

// Round 16
// 218.139 us; speedup vs baseline: 1.3919x; 1.0464x over previous
//
#include <hip/hip_runtime.h>

// ---------------------------------------------------------------------------
// AttentionMultiHead: x[8,1024,1024] f32, per-head Wq/Wk/Wv[16,1024,64]+bias,
// Wo[1024,64]+bo. Outputs: z_out[8,1024,64] f32, att[8,16,1024,1024] f32 (raw).
//
// Ledger after R15 (228.3us, best): attn ~120 (nt-write bound ~100),
// gemm ~55 (~900TF structure ceiling), pack ~25, out ~8, gaps ~15.
// Confirmed mechanisms: VMEM request-rate (R11 -70, R12 -49), nt no-pollution
// (R7 -58, R13 regression proof), single-buffered 128-kv attn (R14/R15).
// R16 (attn UNTOUCHED): (1) pack_w LDS-transpose - kills 256B-stride 4B
// gather (same request-rate pathology as attn's R11); (2) gemm_qkv BK=64 -
// halves barrier-drain count; 128B LDS rows get the attn-proven chunk-XOR
// swizzle (linear would be 32-way bank conflict, G4).
// ---------------------------------------------------------------------------

typedef __bf16 bf16x8 __attribute__((ext_vector_type(8)));
typedef float f32x4 __attribute__((ext_vector_type(4)));
typedef unsigned short u16x8 __attribute__((ext_vector_type(8)));
typedef unsigned short u16x4 __attribute__((ext_vector_type(4)));

typedef __attribute__((address_space(1))) unsigned int as1_u32;
typedef __attribute__((address_space(3))) unsigned int as3_u32;

#define MFMA16(a, b, c) __builtin_amdgcn_mfma_f32_16x16x32_bf16(a, b, c, 0, 0, 0)

__device__ __forceinline__ void gload_lds16(const void* g, void* l) {
  __builtin_amdgcn_global_load_lds((const as1_u32*)g, (as3_u32*)l, 16, 0, 0);
}

__device__ __forceinline__ unsigned short f2bf(float f) {
  union { float f; unsigned u; } a; a.f = f;
  unsigned r = a.u + 0x7FFFu + ((a.u >> 16) & 1u);  // RNE
  return (unsigned short)(r >> 16);
}

// ---------------- fused pack kernel ----------------
// blocks [0,8192): x->bf16 (float4 copy); [8192,8960): W transpose via LDS
// tile (coalesced float4 reads, u16x8 writes); [8960,9229): Wop + bqkv.
__global__ __launch_bounds__(256) void pack_all(const float* __restrict__ x, const float* __restrict__ Wq,
                                                const float* __restrict__ Wk, const float* __restrict__ Wv,
                                                const float* __restrict__ Wo, const float* __restrict__ bq,
                                                const float* __restrict__ bk, const float* __restrict__ bv,
                                                ushort* __restrict__ xb, ushort* __restrict__ Wp,
                                                ushort* __restrict__ Wop, float* __restrict__ bqkv) {
  __shared__ float tile[64][65];   // 65-pad: transpose col reads <=2-way (free)
  const int bid = blockIdx.x;
  if (bid < 8192) {
    const size_t i = ((size_t)bid * 256 + threadIdx.x) * 4;
    const float4 v = *(const float4*)(x + i);
    u16x4 o; o[0] = f2bf(v.x); o[1] = f2bf(v.y); o[2] = f2bf(v.z); o[3] = f2bf(v.w);
    *(u16x4*)(xb + i) = o;
  } else if (bid < 8960) {
    // one block per (proj, h, dtile): transpose W[h][d0..d0+64][0..64] ->
    // Wp rows proj*1024+h*64+kk, cols d0..d0+64.
    const int b3 = bid - 8192;
    const int proj = b3 >> 8, rem = b3 & 255;
    const int h = rem >> 4, dt = rem & 15;
    const float* W = proj == 0 ? Wq : (proj == 1 ? Wk : Wv);
    const int r = threadIdx.x >> 2, cc = (threadIdx.x & 3) * 16;
    const float* src = W + ((size_t)h * 1024 + dt * 64 + r) * 64 + cc;
#pragma unroll
    for (int i = 0; i < 4; ++i) {
      const float4 v = *(const float4*)(src + i * 4);
      tile[r][cc + i * 4 + 0] = v.x; tile[r][cc + i * 4 + 1] = v.y;
      tile[r][cc + i * 4 + 2] = v.z; tile[r][cc + i * 4 + 3] = v.w;
    }
    __syncthreads();
    const int kk = threadIdx.x >> 2, dc = (threadIdx.x & 3) * 16;
    u16x8 o0, o1;
#pragma unroll
    for (int i = 0; i < 8; ++i) o0[i] = f2bf(tile[dc + i][kk]);
#pragma unroll
    for (int i = 0; i < 8; ++i) o1[i] = f2bf(tile[dc + 8 + i][kk]);
    ushort* dst = Wp + (size_t)(proj * 1024 + h * 64 + kk) * 1024 + dt * 64 + dc;
    *(u16x8*)dst = o0;
    *(u16x8*)(dst + 8) = o1;
  } else {
    const int idx = (bid - 8960) * 256 + threadIdx.x;
    if (idx < 65536) {
      const int n = idx >> 10, c = idx & 1023;   // Wop[n][c] = Wo[c][n]
      Wop[idx] = f2bf(Wo[c * 64 + n]);
    } else if (idx < 65536 + 3072) {
      const int n = idx - 65536;
      const int proj = n >> 10;
      const float* bb = proj == 0 ? bq : (proj == 1 ? bk : bv);
      bqkv[n] = bb[n & 1023];
    }
  }
}

// ---------------- QKV projection GEMM (BK=64, chunk-XOR swizzled LDS) -------
// C[8192][3072] = relu(xb @ Wp^T + bqkv). 128x128 tile, BK=64, 16 K-steps
// (half the barrier drains of BK=32). 128B LDS rows: source col-chunk
// pre-swizzled by row&7 (attn-proven pattern) -> frag reads 2-way max.
// by-inner XCD swizzle (A-panels L2-resident per XCD).
__global__ __launch_bounds__(256) void gemm_qkv(const ushort* __restrict__ xb, const ushort* __restrict__ Wp,
                                                const float* __restrict__ bqkv, ushort* __restrict__ qo,
                                                ushort* __restrict__ ko, ushort* __restrict__ vTo) {
  __shared__ ushort As[128 * 64], Bs[128 * 64];   // 32 KB
  const int bid = blockIdx.x;                 // 1536 blocks
  const int xcd = bid & 7, idx = bid >> 3;
  const int bx = idx >> 3, by = xcd * 8 + (idx & 7);
  const int t = threadIdx.x, w = t >> 6, l = t & 63, lg = l >> 4, lr = l & 15;
  const int m0 = by * 128, n0 = bx * 128;
  const int wm = w >> 1, wn = w & 1;
  const int r8 = l >> 3, ch = l & 7;          // staging lane geometry
  f32x4 acc[4][4] = {};
  for (int kt = 0; kt < 16; ++kt) {
    __syncthreads();
#pragma unroll
    for (int c2 = 0; c2 < 4; ++c2) {
      const int c = w * 4 + c2;               // chunk 0..15 (8 rows x 128B)
      const int row = c * 8 + r8;             // 0..127
      const int sc = (ch ^ (row & 7)) * 8;    // pre-swizzled source col
      gload_lds16(xb + (size_t)(m0 + row) * 1024 + kt * 64 + sc, &As[c * 512]);
      gload_lds16(Wp + (size_t)(n0 + row) * 1024 + kt * 64 + sc, &Bs[c * 512]);
    }
    __syncthreads();
#pragma unroll
    for (int hk = 0; hk < 2; ++hk) {          // two K=32 halves of the 64-tile
      bf16x8 af[4], bfr[4];
#pragma unroll
      for (int mt = 0; mt < 4; ++mt) {
        const int row = wm * 64 + mt * 16 + lr;
        af[mt] = *(const bf16x8*)(&As[row * 64 + (((hk * 4 + lg) ^ (row & 7)) * 8)]);
      }
#pragma unroll
      for (int nt = 0; nt < 4; ++nt) {
        const int row = wn * 64 + nt * 16 + lr;
        bfr[nt] = *(const bf16x8*)(&Bs[row * 64 + (((hk * 4 + lg) ^ (row & 7)) * 8)]);
      }
#pragma unroll
      for (int mt = 0; mt < 4; ++mt)
#pragma unroll
        for (int nt = 0; nt < 4; ++nt)
          acc[mt][nt] = MFMA16(af[mt], bfr[nt], acc[mt][nt]);
    }
  }
  // epilogue: bias + relu -> bf16. proj uniform across the wave (16-aligned n-chunks).
#pragma unroll
  for (int nt = 0; nt < 4; ++nt) {
    const int n = n0 + wn * 64 + nt * 16 + lr;
    const float bias = bqkv[n];
    const int proj = n >> 10, h = (n >> 6) & 15, dk = n & 63;
#pragma unroll
    for (int mt = 0; mt < 4; ++mt) {
      const int mb = m0 + wm * 64 + mt * 16 + lg * 4;  // j-quad base, same b & 4-aligned s
      const int b = mb >> 10, s = mb & 1023;
      float vv[4];
#pragma unroll
      for (int j = 0; j < 4; ++j) {
        float a = acc[mt][nt][j] + bias;
        vv[j] = a > 0.f ? a : 0.f;
      }
      if (proj == 2) {
        u16x4 o; o[0] = f2bf(vv[0]); o[1] = f2bf(vv[1]); o[2] = f2bf(vv[2]); o[3] = f2bf(vv[3]);
        *(u16x4*)(vTo + ((size_t)(b * 16 + h) * 64 + dk) * 1024 + s) = o;
      } else {
        ushort* op = proj == 0 ? qo : ko;
#pragma unroll
        for (int j = 0; j < 4; ++j)
          op[((size_t)(b * 16 + h) * 1024 + s + j) * 64 + dk] = f2bf(vv[j]);
      }
    }
  }
}

// ---------------- fused attention (EXACT R12/R15: LDS K/V, nt 128B flush) ----
__global__ __launch_bounds__(256) void attn_kernel(const ushort* __restrict__ qg, const ushort* __restrict__ kg,
                                                   const ushort* __restrict__ vT, float* __restrict__ att,
                                                   ushort* __restrict__ heads) {
  const int bid = blockIdx.x;                 // 2048
  const int swz = (bid & 7) * 256 + (bid >> 3);
  const int qt = swz & 15, bh = swz >> 4;
  const int t = threadIdx.x, w = t >> 6, l = t & 63;
  const int lg = l >> 4, lr = l & 15;
  __shared__ ushort Ks[128 * 64];         // 16 KB, chunk-swizzled rows
  __shared__ ushort Vs[64 * 128];         // 16 KB, chunk-swizzled rows
  __shared__ ushort p_q[4][16][40];       // 5 KB, P quarter (32 kv), reused
  __shared__ float s_st[4][16][40];       // 10 KB, score quarter (32 kv), reused

  const ushort* qb = qg + (size_t)bh * 65536;
  const ushort* kb = kg + (size_t)bh * 65536;
  const ushort* vb = vT + (size_t)bh * 65536;
  const int qrow0 = qt * 64 + w * 16;

  const bf16x8 qf0 = *(const bf16x8*)(qb + (qrow0 + lr) * 64 + lg * 8);
  const bf16x8 qf1 = *(const bf16x8*)(qb + (qrow0 + lr) * 64 + 32 + lg * 8);

  const int krow = l >> 3, kch = l & 7;    // K: 8 rows x 8 chunks(16B)
  const int vrow = l >> 4, vch = l & 15;   // V: 4 rows x 16 chunks(16B)
  const int frow = l >> 3, fcol = (l & 7) * 4;  // flush: 8 rows x 128B per instr

  const float C2 = 0.125f * 1.44269504f;   // 1/sqrt(64) in exp2 domain
  f32x4 oacc[4] = {};
  float lsum = 0.f;
  float* attw = att + ((size_t)bh * 1024 + qrow0) * 1024;

  for (int g = 0; g < 8; ++g) {
    const int kv0 = g * 128;
    __syncthreads();   // all waves done reading previous group's tiles
#pragma unroll
    for (int c2 = 0; c2 < 4; ++c2) {
      const int call = w * 4 + c2;
      const int r = call * 8 + krow;       // K local row 0..127
      gload_lds16(kb + (size_t)(kv0 + r) * 64 + ((kch ^ (r & 7)) * 8), &Ks[call * 512]);
      const int rv = call * 4 + vrow;      // V local row (dk) 0..63
      gload_lds16(vb + (size_t)rv * 1024 + kv0 + ((vch ^ (rv & 15)) * 8), &Vs[call * 512]);
    }
    __syncthreads();   // stage complete
    // QK^T from LDS: sf[f][j] = S[q=lr][kv = kv0 + f*16 + lg*4 + j]
    f32x4 sf[8];
#pragma unroll
    for (int f = 0; f < 8; ++f) {
      const int r = f * 16 + lr;
      const bf16x8 kf0 = *(const bf16x8*)(&Ks[r * 64 + ((lg ^ (r & 7)) * 8)]);
      const bf16x8 kf1 = *(const bf16x8*)(&Ks[r * 64 + (((4 + lg) ^ (r & 7)) * 8)]);
      f32x4 s = {};
      s = MFMA16(kf0, qf0, s);
      s = MFMA16(kf1, qf1, s);
      sf[f] = s;
    }
    // 4 slices of 32 kv: exp/pack + score-stage -> nt line flush + PV
#pragma unroll
    for (int s = 0; s < 4; ++s) {
#pragma unroll
      for (int fi = 0; fi < 2; ++fi) {
        const int f = 2 * s + fi;
        u16x4 pk;
#pragma unroll
        for (int j = 0; j < 4; ++j) {
          const float p = exp2f(sf[f][j] * C2);
          lsum += p;
          pk[j] = f2bf(p);
        }
        *(u16x4*)(&p_q[w][lr][fi * 16 + lg * 4]) = pk;
        *(f32x4*)(&s_st[w][lr][fi * 16 + lg * 4]) = sf[f];
      }
      // per-wave LDS region; DS ops wave-program-order; wait for writes
      asm volatile("s_waitcnt lgkmcnt(0)" ::: "memory");
      __builtin_amdgcn_sched_barrier(0);
      const bf16x8 pa = *(const bf16x8*)(&p_q[w][lr][lg * 8]);
      // flush this slice: 2 instrs x 8 rows x 128B fully-covered aligned lines
#pragma unroll
      for (int i = 0; i < 2; ++i) {
        const int r = i * 8 + frow;
        const f32x4 fv = *(const f32x4*)(&s_st[w][r][fcol]);
        __builtin_nontemporal_store(fv,
            (f32x4*)(attw + (size_t)r * 1024 + kv0 + s * 32 + fcol));
      }
      // PV for this slice (LDS/reg only -> store retire shadow)
#pragma unroll
      for (int nt = 0; nt < 4; ++nt) {
        const int r = nt * 16 + lr;
        const bf16x8 vf = *(const bf16x8*)(&Vs[r * 128 + (((s * 4 + lg) ^ lr) * 8)]);
        oacc[nt] = MFMA16(pa, vf, oacc[nt]);
      }
    }
  }
  // row sums: reduce lane partials across lg groups
  lsum += __shfl_xor(lsum, 16, 64);
  lsum += __shfl_xor(lsum, 32, 64);
  float rdiv[4];
#pragma unroll
  for (int j = 0; j < 4; ++j) rdiv[j] = 1.f / __shfl(lsum, lg * 4 + j, 16);
  const int b = bh >> 4, h = bh & 15;
#pragma unroll
  for (int nt = 0; nt < 4; ++nt)
#pragma unroll
    for (int j = 0; j < 4; ++j)
      __builtin_nontemporal_store(f2bf(oacc[nt][j] * rdiv[j]),
          heads + (size_t)(b * 1024 + qrow0 + lg * 4 + j) * 1024 + h * 64 + nt * 16 + lr);
}

// ---------------- output GEMM: z_out = relu(heads @ Wo + bo) ----------------
__global__ __launch_bounds__(256) void gemm_out(const ushort* __restrict__ z, const ushort* __restrict__ Wop,
                                                const float* __restrict__ bo, float* __restrict__ out) {
  __shared__ float red[2][16][64];
  const int t = threadIdx.x, w = t >> 6, l = t & 63, lg = l >> 4, lr = l & 15;
  const int wm = w & 1, kh = w >> 1;
  const int m0 = blockIdx.x * 32 + wm * 16;
  f32x4 acc[4] = {};
  for (int kk = kh * 16; kk < kh * 16 + 16; ++kk) {
    bf16x8 af = *(const bf16x8*)(z + (size_t)(m0 + lr) * 1024 + kk * 32 + lg * 8);
#pragma unroll
    for (int nt = 0; nt < 4; ++nt) {
      bf16x8 bfr = *(const bf16x8*)(Wop + (size_t)(nt * 16 + lr) * 1024 + kk * 32 + lg * 8);
      acc[nt] = MFMA16(af, bfr, acc[nt]);
    }
  }
  if (kh == 1) {
#pragma unroll
    for (int nt = 0; nt < 4; ++nt)
#pragma unroll
      for (int j = 0; j < 4; ++j) red[wm][lg * 4 + j][nt * 16 + lr] = acc[nt][j];
  }
  __syncthreads();
  if (kh == 0) {
#pragma unroll
    for (int nt = 0; nt < 4; ++nt) {
      const int n = nt * 16 + lr;
      const float bb = bo[n];
#pragma unroll
      for (int j = 0; j < 4; ++j) {
        const int m = m0 + lg * 4 + j;
        float vv = acc[nt][j] + red[wm][lg * 4 + j][n] + bb;
        out[(size_t)m * 64 + n] = vv > 0.f ? vv : 0.f;
      }
    }
  }
}

// ---------------------------------------------------------------------------
extern "C" void kernel_launch(void* const* d_in, const int* in_sizes, int n_in,
                              void* d_out, int out_size, void* d_ws, size_t ws_size,
                              hipStream_t stream) {
  const float* x  = (const float*)d_in[0];
  const float* Wq = (const float*)d_in[1];
  const float* bq = (const float*)d_in[2];
  const float* Wk = (const float*)d_in[3];
  const float* bk = (const float*)d_in[4];
  const float* Wv = (const float*)d_in[5];
  const float* bv = (const float*)d_in[6];
  const float* Wo = (const float*)d_in[7];
  const float* bo = (const float*)d_in[8];
  float* out = (float*)d_out;            // z_out: 8*1024*64 = 524288 f32
  float* att = out + 524288;             // att:   8*16*1024*1024 f32

  // workspace layout (~92 MB)
  char* ws = (char*)d_ws;
  size_t off = 0;
  ushort* xb  = (ushort*)(ws + off); off += (size_t)8192 * 1024 * 2;
  ushort* Wp  = (ushort*)(ws + off); off += (size_t)3072 * 1024 * 2;
  ushort* Wop = (ushort*)(ws + off); off += (size_t)64 * 1024 * 2;
  float* bqkv = (float*)(ws + off);  off += (size_t)3072 * 4;
  ushort* q   = (ushort*)(ws + off); off += (size_t)128 * 1024 * 64 * 2;
  ushort* k   = (ushort*)(ws + off); off += (size_t)128 * 1024 * 64 * 2;
  ushort* vT  = (ushort*)(ws + off); off += (size_t)128 * 64 * 1024 * 2;
  ushort* hds = (ushort*)(ws + off); off += (size_t)8192 * 1024 * 2;
  (void)ws_size; (void)in_sizes; (void)n_in; (void)out_size;

  pack_all<<<dim3(9229), dim3(256), 0, stream>>>(x, Wq, Wk, Wv, Wo, bq, bk, bv,
                                                 xb, Wp, Wop, bqkv);
  gemm_qkv<<<dim3(1536), dim3(256), 0, stream>>>(xb, Wp, bqkv, q, k, vT);
  attn_kernel<<<dim3(2048), dim3(256), 0, stream>>>(q, k, vT, att, hds);
  gemm_out<<<dim3(256), dim3(256), 0, stream>>>(hds, Wop, bo, out);
}